// Round 1
// baseline (13624.905 us; speedup 1.0000x reference)
//
#include <hip/hip_runtime.h>
#include <hip/hip_bf16.h>

// ---------------------------------------------------------------------------
// SparseDecoderWave — fp32 correctness-first pipeline.
// Heavy convs: templated LDS-tiled direct conv with fused concat/up2x/masks.
// ---------------------------------------------------------------------------

#define KC 4   // input-channel chunk per LDS stage

// MODE 0: stem  (edge pad, in = x32 direct, no activation)
// MODE 1: up1   (reflect pad, inA = up2x(x_d0), inB = x16, leaky)
// MODE 2: up2   (reflect, inA = up2x(x_d1*upm)*convam, inB = x8*convam, leaky, *wavem)
// MODE 3: up3   (same as 2 with xa/x4)
template<int MODE, int CA, int CB, int HH, int WW, int TX, int TY, int OCT>
__global__ __launch_bounds__(256)
void conv3x3_k(const float* __restrict__ inA, const float* __restrict__ inB,
               const float* __restrict__ wgt, const float* __restrict__ bias,
               const float* __restrict__ upm, const float* __restrict__ convam,
               const float* __restrict__ wavem,
               float* __restrict__ out, int OC)
{
    constexpr int CT    = CA + CB;
    constexpr int PW    = TX + 2;
    constexpr int PH    = TY + 2;
    constexpr int PATCH = PW * PH;
    constexpr int RO    = OCT / 16;   // output channels per thread
    constexpr int WSTR  = OCT + 4;    // LDS weight row stride (bank de-phase, keeps 16B align)
    constexpr int XT    = WW / TX;

    __shared__ float ilds[KC][PH][PW];
    __shared__ float wlds[KC][9][WSTR];

    const int tid  = threadIdx.x;
    const int b    = blockIdx.z;
    const int oc0  = blockIdx.y * OCT;
    const int ty0  = (blockIdx.x / XT) * TY;
    const int tx0g = (blockIdx.x % XT) * TX;

    const int oc_t = tid & 15;   // 16 oc-threads * RO
    const int px_t = tid >> 4;   // 16 px-threads * 4 px
    const int p0   = px_t * 4;
    const int ty   = p0 / TX;    // fixed row within tile (4-px group never straddles rows)
    const int tx0  = p0 % TX;

    float acc[RO][4];
#pragma unroll
    for (int i = 0; i < RO; ++i)
#pragma unroll
        for (int j = 0; j < 4; ++j) acc[i][j] = 0.f;

    for (int ic0 = 0; ic0 < CT; ic0 += KC) {
        // ---- stage input patch (pad-resolved, mode-fused fetch) ----
        for (int i = tid; i < KC * PATCH; i += 256) {
            int ic_l = i / PATCH;
            int r2   = i - ic_l * PATCH;
            int r    = r2 / PW;
            int c    = r2 - r * PW;
            int y = ty0 + r - 1, x = tx0g + c - 1;
            if constexpr (MODE == 0) {           // edge (replicate)
                y = min(max(y, 0), HH - 1);
                x = min(max(x, 0), WW - 1);
            } else {                             // reflect
                y = (y < 0) ? -y : ((y >= HH) ? 2 * HH - 2 - y : y);
                x = (x < 0) ? -x : ((x >= WW) ? 2 * WW - 2 - x : x);
            }
            const int ic = ic0 + ic_l;
            float v;
            if constexpr (MODE == 0) {
                v = inA[((size_t)(b * CA + ic) * HH + y) * WW + x];
            } else if constexpr (MODE == 1) {
                if (ic < CA)
                    v = inA[((size_t)(b * CA + ic) * (HH / 2) + (y >> 1)) * (WW / 2) + (x >> 1)];
                else
                    v = inB[((size_t)(b * CB + (ic - CA)) * HH + y) * WW + x];
            } else {
                const float cm = convam[((size_t)b * HH + y) * WW + x];
                if (ic < CA)
                    v = inA[((size_t)(b * CA + ic) * (HH / 2) + (y >> 1)) * (WW / 2) + (x >> 1)]
                        * upm[((size_t)b * (HH / 2) + (y >> 1)) * (WW / 2) + (x >> 1)] * cm;
                else
                    v = inB[((size_t)(b * CB + (ic - CA)) * HH + y) * WW + x] * cm;
            }
            ilds[ic_l][r][c] = v;
        }
        // ---- stage weights: w[oc][ic][3][3]; 36 contiguous floats per oc ----
        for (int i = tid; i < KC * 9 * OCT; i += 256) {
            int oc_l = i / 36;
            int r    = i - oc_l * 36;
            int kc   = r / 9;
            int t    = r - kc * 9;
            int oc   = oc0 + oc_l;
            float v  = (oc < OC) ? wgt[((size_t)oc * CT + (ic0 + kc)) * 9 + t] : 0.f;
            wlds[kc][t][oc_l] = v;
        }
        __syncthreads();
        // ---- compute ----
#pragma unroll
        for (int kc = 0; kc < KC; ++kc) {
#pragma unroll
            for (int ky = 0; ky < 3; ++ky) {
                float rv[6];
#pragma unroll
                for (int j = 0; j < 6; ++j) rv[j] = ilds[kc][ty + ky][tx0 + j];
#pragma unroll
                for (int kx = 0; kx < 3; ++kx) {
                    float wr[RO];
#pragma unroll
                    for (int i = 0; i < RO; ++i) wr[i] = wlds[kc][ky * 3 + kx][oc_t * RO + i];
#pragma unroll
                    for (int i = 0; i < RO; ++i)
#pragma unroll
                        for (int j = 0; j < 4; ++j)
                            acc[i][j] = fmaf(wr[i], rv[kx + j], acc[i][j]);
                }
            }
        }
        __syncthreads();
    }

    // ---- epilogue ----
    const int y = ty0 + ty;
#pragma unroll
    for (int i = 0; i < RO; ++i) {
        const int oc = oc0 + oc_t * RO + i;
        if (oc >= OC) continue;
        const float bv = bias[oc];
#pragma unroll
        for (int j = 0; j < 4; ++j) {
            const int x = tx0g + tx0 + j;
            float v = acc[i][j] + bv;
            if constexpr (MODE >= 1) v = v > 0.f ? v : 0.2f * v;
            if constexpr (MODE >= 2) v *= wavem[((size_t)b * HH + y) * WW + x];
            out[((size_t)(b * OC + oc) * HH + y) * WW + x] = v;
        }
    }
}

// ---- wave convs: 3 detail channels (zero pad) + optional LL (edge pad) ----
template<int C, int H, int W, int PARTS, bool HAS_LL>
__global__ __launch_bounds__(256)
void wave_k(const float* __restrict__ in,
            const float* __restrict__ wh, const float* __restrict__ bh,
            const float* __restrict__ wll, const float* __restrict__ bll,
            const float* __restrict__ mhalf,   // half-res wavelet mask (nullable)
            float scale_h,
            float* __restrict__ outh, float* __restrict__ outll)
{
    const int g = blockIdx.x * 256 + threadIdx.x;
    constexpr int N = 4 * H * W * PARTS;
    if (g >= N) return;
    const int part = g % PARTS;
    const int pix  = g / PARTS;
    const int x = pix % W;
    const int y = (pix / W) % H;
    const int b = pix / (W * H);
    constexpr int CS = C / PARTS;
    const int icb = part * CS;

    float a0 = 0.f, a1 = 0.f, a2 = 0.f, all = 0.f;
    for (int ic = icb; ic < icb + CS; ++ic) {
        const float* ip = in + (size_t)(b * C + ic) * H * W;
        const float* w0 = wh + ((size_t)(0 * C + ic)) * 9;
        const float* w1 = wh + ((size_t)(1 * C + ic)) * 9;
        const float* w2 = wh + ((size_t)(2 * C + ic)) * 9;
#pragma unroll
        for (int ky = 0; ky < 3; ++ky) {
            const int yy = y + ky - 1;
            const int yc = min(max(yy, 0), H - 1);
            const bool yin = (yy >= 0) && (yy < H);
#pragma unroll
            for (int kx = 0; kx < 3; ++kx) {
                const int xx = x + kx - 1;
                const int xc = min(max(xx, 0), W - 1);
                const bool inr = yin && (xx >= 0) && (xx < W);
                const float v  = ip[(size_t)yc * W + xc];
                const float vz = inr ? v : 0.f;
                const int t = ky * 3 + kx;
                a0 = fmaf(w0[t], vz, a0);
                a1 = fmaf(w1[t], vz, a1);
                a2 = fmaf(w2[t], vz, a2);
                if (HAS_LL) all = fmaf(wll[(size_t)ic * 9 + t], v, all);
            }
        }
    }
    // reduce K-parts across adjacent lanes
#pragma unroll
    for (int off = 1; off < PARTS; off <<= 1) {
        a0 += __shfl_xor(a0, off);
        a1 += __shfl_xor(a1, off);
        a2 += __shfl_xor(a2, off);
        if (HAS_LL) all += __shfl_xor(all, off);
    }
    if (part == 0) {
        float wm = 1.f;
        if (mhalf) wm = mhalf[((size_t)b * (H / 2) + (y >> 1)) * (W / 2) + (x >> 1)];
        outh[((size_t)(b * 3 + 0) * H + y) * W + x] = (a0 + bh[0]) * scale_h * wm;
        outh[((size_t)(b * 3 + 1) * H + y) * W + x] = (a1 + bh[1]) * scale_h * wm;
        outh[((size_t)(b * 3 + 2) * H + y) * W + x] = (a2 + bh[2]) * scale_h * wm;
        if (HAS_LL) outll[((size_t)b * H + y) * W + x] = (all + bll[0]) * 8.0f;
    }
}

// ---- inverse Haar DWT: (B,1,H,W)+(B,3,H,W) -> (B,1,2H,2W) ----
template<int H, int W>
__global__ __launch_bounds__(256)
void idwt_k(const float* __restrict__ ll, const float* __restrict__ h,
            float* __restrict__ out)
{
    const int g = blockIdx.x * 256 + threadIdx.x;
    constexpr int N = 4 * H * W;
    if (g >= N) return;
    const int x = g % W;
    const int y = (g / W) % H;
    const int b = g / (W * H);
    const float l  = ll[g];
    const float lh = h[((size_t)(b * 3 + 0) * H + y) * W + x];
    const float hl = h[((size_t)(b * 3 + 1) * H + y) * W + x];
    const float hh = h[((size_t)(b * 3 + 2) * H + y) * W + x];
    const float x00 = (l + lh + hl + hh) * 0.5f;
    const float x01 = (l - lh + hl - hh) * 0.5f;
    const float x10 = (l + lh - hl - hh) * 0.5f;
    const float x11 = (l - lh - hl + hh) * 0.5f;
    float* ob = out + (size_t)b * (2 * H) * (2 * W);
    ob[(size_t)(2 * y) * (2 * W) + 2 * x]         = x00;
    ob[(size_t)(2 * y) * (2 * W) + 2 * x + 1]     = x01;
    ob[(size_t)(2 * y + 1) * (2 * W) + 2 * x]     = x10;
    ob[(size_t)(2 * y + 1) * (2 * W) + 2 * x + 1] = x11;
}

// ---- global (max-min)*0.1 -> *thr, single block ----
__global__ __launch_bounds__(256)
void minmax_k(const float* __restrict__ p, int n, float* __restrict__ thr)
{
    __shared__ float smax[256], smin[256];
    float mx = -1e30f, mn = 1e30f;
    for (int i = threadIdx.x; i < n; i += 256) {
        const float v = p[i];
        mx = fmaxf(mx, v);
        mn = fminf(mn, v);
    }
    smax[threadIdx.x] = mx;
    smin[threadIdx.x] = mn;
    __syncthreads();
    for (int s = 128; s > 0; s >>= 1) {
        if (threadIdx.x < s) {
            smax[threadIdx.x] = fmaxf(smax[threadIdx.x], smax[threadIdx.x + s]);
            smin[threadIdx.x] = fminf(smin[threadIdx.x], smin[threadIdx.x + s]);
        }
        __syncthreads();
    }
    if (threadIdx.x == 0) *thr = (smax[0] - smin[0]) * 0.1f;
}

// ---- mask = (max_c |h_c| > thr) ----
template<int H, int W>
__global__ __launch_bounds__(256)
void mask_k(const float* __restrict__ h, const float* __restrict__ thr,
            float* __restrict__ mask)
{
    const int g = blockIdx.x * 256 + threadIdx.x;
    constexpr int N = 4 * H * W;
    if (g >= N) return;
    const int x = g % W;
    const int y = (g / W) % H;
    const int b = g / (W * H);
    const float t  = *thr;
    const float v0 = fabsf(h[((size_t)(b * 3 + 0) * H + y) * W + x]);
    const float v1 = fabsf(h[((size_t)(b * 3 + 1) * H + y) * W + x]);
    const float v2 = fabsf(h[((size_t)(b * 3 + 2) * H + y) * W + x]);
    mask[g] = (fmaxf(v0, fmaxf(v1, v2)) > t) ? 1.f : 0.f;
}

// ---- binary dilation, radius R (Chebyshev), same-res ----
template<int H, int W, int R>
__global__ __launch_bounds__(256)
void dilate_k(const float* __restrict__ m, float* __restrict__ o)
{
    const int g = blockIdx.x * 256 + threadIdx.x;
    constexpr int N = 4 * H * W;
    if (g >= N) return;
    const int x = g % W;
    const int y = (g / W) % H;
    const int b = g / (W * H);
    float v = 0.f;
    for (int dy = -R; dy <= R; ++dy) {
        const int yy = y + dy;
        if (yy < 0 || yy >= H) continue;
        for (int dx = -R; dx <= R; ++dx) {
            const int xx = x + dx;
            if (xx < 0 || xx >= W) continue;
            v = fmaxf(v, m[((size_t)b * H + yy) * W + xx]);
        }
    }
    o[g] = (v > 0.f) ? 1.f : 0.f;
}

// ---- masks on 2x grid: conva (r=2) & wave (r=1) of maxpool(up2x(mask)) ----
template<int H, int W>
__global__ __launch_bounds__(256)
void masksfull_k(const float* __restrict__ m, float* __restrict__ conva,
                 float* __restrict__ wavem)
{
    const int g = blockIdx.x * 256 + threadIdx.x;
    constexpr int H2 = 2 * H, W2 = 2 * W;
    constexpr int N = 4 * H2 * W2;
    if (g >= N) return;
    const int x = g % W2;
    const int y = (g / W2) % H2;
    const int b = g / (W2 * H2);
    float c5 = 0.f, c3 = 0.f;
    for (int dy = -2; dy <= 2; ++dy) {
        const int yy = y + dy;
        if (yy < 0 || yy >= H2) continue;
        const int my = yy >> 1;
        for (int dx = -2; dx <= 2; ++dx) {
            const int xx = x + dx;
            if (xx < 0 || xx >= W2) continue;
            const float v = m[((size_t)b * H + my) * W + (xx >> 1)];
            c5 = fmaxf(c5, v);
            if (dy >= -1 && dy <= 1 && dx >= -1 && dx <= 1) c3 = fmaxf(c3, v);
        }
    }
    conva[g] = (c5 > 0.f) ? 1.f : 0.f;
    wavem[g] = (c3 > 0.f) ? 1.f : 0.f;
}

// ---------------------------------------------------------------------------
// workspace layout (floats)
// ---------------------------------------------------------------------------
static constexpr size_t OFF_XD0   = 0;                       // 4*1104*10*32
static constexpr size_t OFF_XD1   = OFF_XD0 + 1413120;       // 4*552*20*64
static constexpr size_t OFF_XA    = OFF_XD1 + 2826240;       // 4*276*40*128
static constexpr size_t OFF_XB    = OFF_XA + 5652480;        // 4*138*80*256
static constexpr size_t OFF_LL1   = OFF_XB + 11304960;       // 4*20*64
static constexpr size_t OFF_H1    = OFF_LL1 + 5120;          // 4*3*20*64
static constexpr size_t OFF_LLB   = OFF_H1 + 15360;          // 4*40*128
static constexpr size_t OFF_H2    = OFF_LLB + 20480;         // 4*3*40*128
static constexpr size_t OFF_LLC   = OFF_H2 + 61440;          // 4*80*256
static constexpr size_t OFF_H3    = OFF_LLC + 81920;         // 4*3*80*256
static constexpr size_t OFF_MASK1 = OFF_H3 + 245760;         // 4*20*64
static constexpr size_t OFF_UPM1  = OFF_MASK1 + 5120;        // 4*20*64
static constexpr size_t OFF_CAM1  = OFF_UPM1 + 5120;         // 4*40*128
static constexpr size_t OFF_WM1   = OFF_CAM1 + 20480;        // 4*40*128
static constexpr size_t OFF_MASK2 = OFF_WM1 + 20480;         // 4*40*128
static constexpr size_t OFF_UPM2  = OFF_MASK2 + 20480;       // 4*40*128
static constexpr size_t OFF_CAM2  = OFF_UPM2 + 20480;        // 4*80*256
static constexpr size_t OFF_WM2   = OFF_CAM2 + 81920;        // 4*80*256
static constexpr size_t OFF_RED   = OFF_WM2 + 81920;         // 8

extern "C" void kernel_launch(void* const* d_in, const int* in_sizes, int n_in,
                              void* d_out, int out_size, void* d_ws, size_t ws_size,
                              hipStream_t stream)
{
    const float* x32     = (const float*)d_in[0];
    const float* x16     = (const float*)d_in[1];
    const float* x8      = (const float*)d_in[2];
    const float* x4      = (const float*)d_in[3];
    const float* conv2_w = (const float*)d_in[4];
    const float* conv2_b = (const float*)d_in[5];
    const float* up1_w   = (const float*)d_in[6];
    const float* up1_b   = (const float*)d_in[7];
    const float* w1ll_w  = (const float*)d_in[8];
    const float* w1ll_b  = (const float*)d_in[9];
    const float* w1_w    = (const float*)d_in[10];
    const float* w1_b    = (const float*)d_in[11];
    const float* up2_w   = (const float*)d_in[12];
    const float* up2_b   = (const float*)d_in[13];
    const float* w2_w    = (const float*)d_in[14];
    const float* w2_b    = (const float*)d_in[15];
    const float* up3_w   = (const float*)d_in[16];
    const float* up3_b   = (const float*)d_in[17];
    const float* w3_w    = (const float*)d_in[18];
    const float* w3_b    = (const float*)d_in[19];

    float* ws    = (float*)d_ws;
    float* xd0   = ws + OFF_XD0;
    float* xd1   = ws + OFF_XD1;
    float* xa    = ws + OFF_XA;
    float* xb    = ws + OFF_XB;
    float* ll1   = ws + OFF_LL1;
    float* h1    = ws + OFF_H1;
    float* llb   = ws + OFF_LLB;
    float* h2    = ws + OFF_H2;
    float* llc   = ws + OFF_LLC;
    float* h3    = ws + OFF_H3;
    float* mask1 = ws + OFF_MASK1;
    float* upm1  = ws + OFF_UPM1;
    float* cam1  = ws + OFF_CAM1;
    float* wm1   = ws + OFF_WM1;
    float* mask2 = ws + OFF_MASK2;
    float* upm2  = ws + OFF_UPM2;
    float* cam2  = ws + OFF_CAM2;
    float* wm2   = ws + OFF_WM2;
    float* red   = ws + OFF_RED;

    // dense stem: x_d0 = conv(x32, edge)        (4,1104,10,32)
    conv3x3_k<0, 2208, 0, 10, 32, 32, 2, 64>
        <<<dim3(5, 18, 4), 256, 0, stream>>>(x32, nullptr, conv2_w, conv2_b,
                                             nullptr, nullptr, nullptr, xd0, 1104);
    // x_d1 = leaky(conv(cat(up2x(x_d0), x16), reflect))   (4,552,20,64)
    conv3x3_k<1, 1104, 384, 20, 64, 64, 1, 128>
        <<<dim3(20, 5, 4), 256, 0, stream>>>(xd0, x16, up1_w, up1_b,
                                             nullptr, nullptr, nullptr, xd1, 552);
    // ll1 = 8*conv(x_d1, edge), h1 = 4*conv(x_d1, zero)
    wave_k<552, 20, 64, 4, true>
        <<<80, 256, 0, stream>>>(xd1, w1_w, w1_b, w1ll_w, w1ll_b, nullptr, 4.0f, h1, ll1);
    idwt_k<20, 64><<<20, 256, 0, stream>>>(ll1, h1, llb);
    minmax_k<<<1, 256, 0, stream>>>(llb, 20480, red + 0);
    mask_k<20, 64><<<20, 256, 0, stream>>>(h1, red + 0, mask1);
    dilate_k<20, 64, 2><<<20, 256, 0, stream>>>(mask1, upm1);
    masksfull_k<20, 64><<<80, 256, 0, stream>>>(mask1, cam1, wm1);
    // xa = leaky(conv(feat1, reflect)) * wave_m           (4,276,40,128)
    conv3x3_k<2, 552, 192, 40, 128, 64, 1, 128>
        <<<dim3(80, 3, 4), 256, 0, stream>>>(xd1, x8, up2_w, up2_b,
                                             upm1, cam1, wm1, xa, 276);
    // h2 = 2*conv(xa, zero) * up2x(mask1)
    wave_k<276, 40, 128, 4, false>
        <<<320, 256, 0, stream>>>(xa, w2_w, w2_b, nullptr, nullptr, mask1, 2.0f, h2, nullptr);
    idwt_k<40, 128><<<80, 256, 0, stream>>>(llb, h2, llc);
    minmax_k<<<1, 256, 0, stream>>>(llc, 81920, red + 1);
    mask_k<40, 128><<<80, 256, 0, stream>>>(h2, red + 1, mask2);
    dilate_k<40, 128, 2><<<80, 256, 0, stream>>>(mask2, upm2);
    masksfull_k<40, 128><<<320, 256, 0, stream>>>(mask2, cam2, wm2);
    // xb = leaky(conv(feat2, reflect)) * wave_m           (4,138,80,256)
    conv3x3_k<3, 276, 96, 80, 256, 64, 1, 128>
        <<<dim3(320, 2, 4), 256, 0, stream>>>(xa, x4, up3_w, up3_b,
                                              upm2, cam2, wm2, xb, 138);
    // h3 = conv(xb, zero) * up2x(mask2)
    wave_k<138, 80, 256, 2, false>
        <<<640, 256, 0, stream>>>(xb, w3_w, w3_b, nullptr, nullptr, mask2, 1.0f, h3, nullptr);
    // final idwt -> d_out (4,1,160,512)
    idwt_k<80, 256><<<320, 256, 0, stream>>>(llc, h3, (float*)d_out);
}

// Round 2
// 3366.489 us; speedup vs baseline: 4.0472x; 4.0472x over previous
//
#include <hip/hip_runtime.h>
#include <hip/hip_bf16.h>
#include <stdint.h>

// ---------------------------------------------------------------------------
// SparseDecoderWave — MFMA bf16 implicit-GEMM pipeline.
// Heavy convs: 16x16x32 bf16 MFMA, channel-last operands, split-bf16 (hi+lo)
// 3-term products for mask-critical convs (stem/up1/up2), single-bf16 up3.
// ---------------------------------------------------------------------------

typedef float f32x4 __attribute__((ext_vector_type(4)));
typedef short s16x8 __attribute__((ext_vector_type(8)));

__device__ __forceinline__ ushort f2bf(float f) {
    uint32_t u = __float_as_uint(f);
    u += 0x7FFFu + ((u >> 16) & 1u);
    return (ushort)(u >> 16);
}
__device__ __forceinline__ float bf2f(ushort h) {
    return __uint_as_float(((uint32_t)h) << 16);
}

// ---- weight repack: w[oc][ic][3][3] fp32 -> Wb[t][ocp][ctp] bf16 (hi/lo) ----
template<bool SPLIT>
__global__ __launch_bounds__(256)
void repack_w_k(const float* __restrict__ w, ushort* __restrict__ whi,
                ushort* __restrict__ wlo, int OC, int CT, int OCP, int CTP)
{
    int gpr = CTP / 8;
    int u = blockIdx.x * 256 + threadIdx.x;
    if (u >= OCP * gpr) return;
    int oc = u / gpr, icg = u - oc * gpr;
    int ic0 = icg * 8;
    for (int t = 0; t < 9; ++t) {
        ushort hi[8], lo[8];
#pragma unroll
        for (int j = 0; j < 8; ++j) {
            int ic = ic0 + j;
            float v = (oc < OC && ic < CT) ? w[((size_t)oc * CT + ic) * 9 + t] : 0.f;
            ushort h = f2bf(v);
            hi[j] = h;
            lo[j] = f2bf(v - bf2f(h));
        }
        size_t o = ((size_t)t * OCP + oc) * CTP + ic0;
        *(uint4*)(whi + o) = *(uint4*)hi;
        if constexpr (SPLIT) *(uint4*)(wlo + o) = *(uint4*)lo;
    }
}

// ---- input repack: [b][c][y][x] fp32 -> [b][y][x][c] bf16 (hi/lo planes) ----
template<bool SPLIT>
__global__ __launch_bounds__(256)
void repack_x_k(const float* __restrict__ in, ushort* __restrict__ hi,
                ushort* __restrict__ lo, int C, int HW)
{
    __shared__ float tile[32][65];
    int b = blockIdx.z;
    int c0 = blockIdx.y * 32;
    int p0 = blockIdx.x * 64;
    for (int e = threadIdx.x; e < 2048; e += 256) {
        int cl = e >> 6, pl = e & 63;
        tile[cl][pl] = in[((size_t)b * C + c0 + cl) * HW + p0 + pl];
    }
    __syncthreads();
    int pl = threadIdx.x >> 2, cg = (threadIdx.x & 3) * 8;
    ushort hv[8], lv[8];
#pragma unroll
    for (int j = 0; j < 8; ++j) {
        float v = tile[cg + j][pl];
        ushort h = f2bf(v);
        hv[j] = h;
        lv[j] = f2bf(v - bf2f(h));
    }
    size_t o = ((size_t)b * HW + p0 + pl) * C + c0 + cg;
    *(uint4*)(hi + o) = *(uint4*)hv;
    if constexpr (SPLIT) *(uint4*)(lo + o) = *(uint4*)lv;
}

// ---- MFMA conv3x3. MODE0 stem(edge), MODE1 up1(reflect), MODE2/3 masked ----
template<int MODE, int CA, int CB, int H, int W, int OC, int OCS, int OCP,
         int CTP, int CAS, int CBS, int UNIT>
__global__ __launch_bounds__(256)
void conv_mfma_k(const ushort* __restrict__ aHi, const ushort* __restrict__ aLo,
                 const ushort* __restrict__ bHi, const ushort* __restrict__ bLo,
                 const ushort* __restrict__ wHi, const ushort* __restrict__ wLo,
                 const float* __restrict__ bias,
                 const float* __restrict__ upm, const float* __restrict__ cam,
                 const float* __restrict__ wvm,
                 ushort* __restrict__ oHi, ushort* __restrict__ oLo)
{
    constexpr bool SPLIT = (MODE < 3);
    constexpr int NPL = SPLIT ? 2 : 1;
    constexpr int ICS = 56;                    // LDS ic-stride: 16B-aligned, spread banks
    constexpr int PLSZ = 6 * 18 * ICS;
    constexpr int CT = CA + CB;
    constexpr int IU = 32 / UNIT;
    constexpr int NU = NPL * 108 * IU;

    __shared__ ushort atile[NPL * PLSZ];

    const int tid = threadIdx.x;
    const int b = blockIdx.z;
    const int oc0 = blockIdx.y * 64;
    constexpr int CBX = W / 16;
    const int y0 = (blockIdx.x / CBX) * 4;
    const int x0 = (blockIdx.x % CBX) * 16;

    const int lane = tid & 63;
    const int wv = tid >> 6;
    const int wm = wv & 1, wn = wv >> 1;
    const int lq = lane >> 4, ln = lane & 15;

    f32x4 acc[2][2];
#pragma unroll
    for (int i = 0; i < 2; ++i)
#pragma unroll
        for (int j = 0; j < 2; ++j) acc[i][j] = {0.f, 0.f, 0.f, 0.f};

    for (int ic0 = 0; ic0 < CTP; ic0 += 32) {
        // -------- stage A tile (pad/upsample/mask fused), channel-last bf16 --------
        for (int i = tid; i < NU; i += 256) {
            int pl = i / (108 * IU);
            int r = i - pl * (108 * IU);
            int pp = r / IU, ug = r - pp * IU;
            int py = pp / 18, px = pp - py * 18;
            int y = y0 + py - 1, x = x0 + px - 1;
            if constexpr (MODE == 0) {
                y = min(max(y, 0), H - 1);
                x = min(max(x, 0), W - 1);
            } else {
                y = (y < 0) ? -y : ((y >= H) ? 2 * H - 2 - y : y);
                x = (x < 0) ? -x : ((x >= W) ? 2 * W - 2 - x : x);
            }
            int ic = ic0 + ug * UNIT;
            uint wb[4] = {0, 0, 0, 0};
            bool live = false;
            const ushort* src = nullptr;
            size_t sidx = 0;
            if (ic < CA) {
                src = (NPL == 2 && pl) ? aLo : aHi;
                if constexpr (MODE == 0)
                    sidx = (((size_t)b * H + y) * W + x) * CAS + ic;
                else
                    sidx = (((size_t)b * (H / 2) + (y >> 1)) * (W / 2) + (x >> 1)) * CAS + ic;
                live = true;
                if constexpr (MODE >= 2) {
                    float mv = upm[((size_t)b * (H / 2) + (y >> 1)) * (W / 2) + (x >> 1)]
                             * cam[((size_t)b * H + y) * W + x];
                    if (mv == 0.f) live = false;
                }
            } else if (ic < CT) {
                src = (NPL == 2 && pl) ? bLo : bHi;
                sidx = (((size_t)b * H + y) * W + x) * CBS + (ic - CA);
                live = true;
                if constexpr (MODE >= 2) {
                    if (cam[((size_t)b * H + y) * W + x] == 0.f) live = false;
                }
            }
            if (live) {
                if constexpr (UNIT == 8) *(uint4*)wb = *(const uint4*)(src + sidx);
                else                     *(uint2*)wb = *(const uint2*)(src + sidx);
            }
            ushort* dst = &atile[pl * PLSZ + (py * 18 + px) * ICS + ug * UNIT];
            if constexpr (UNIT == 8) *(uint4*)dst = *(uint4*)wb;
            else                     *(uint2*)dst = *(uint2*)wb;
        }
        __syncthreads();
        // -------- 9 taps x (2x2 tiles) MFMA --------
        for (int t = 0; t < 9; ++t) {
            const int dy = t / 3, dx = t - dy * 3;
            s16x8 bh[2], bl[2], ah[2], al[2];
#pragma unroll
            for (int n2 = 0; n2 < 2; ++n2) {
                int oc = oc0 + (2 * wn + n2) * 16 + ln;
                size_t o = ((size_t)t * OCP + oc) * CTP + ic0 + lq * 8;
                bh[n2] = *(const s16x8*)(wHi + o);
                if constexpr (SPLIT) bl[n2] = *(const s16x8*)(wLo + o);
            }
#pragma unroll
            for (int m2 = 0; m2 < 2; ++m2) {
                int off = ((2 * wm + m2 + dy) * 18 + ln + dx) * ICS + lq * 8;
                ah[m2] = *(const s16x8*)&atile[off];
                if constexpr (SPLIT) al[m2] = *(const s16x8*)&atile[PLSZ + off];
            }
#pragma unroll
            for (int m2 = 0; m2 < 2; ++m2)
#pragma unroll
                for (int n2 = 0; n2 < 2; ++n2) {
                    acc[m2][n2] = __builtin_amdgcn_mfma_f32_16x16x32_bf16(
                        ah[m2], bh[n2], acc[m2][n2], 0, 0, 0);
                    if constexpr (SPLIT) {
                        acc[m2][n2] = __builtin_amdgcn_mfma_f32_16x16x32_bf16(
                            ah[m2], bl[n2], acc[m2][n2], 0, 0, 0);
                        acc[m2][n2] = __builtin_amdgcn_mfma_f32_16x16x32_bf16(
                            al[m2], bh[n2], acc[m2][n2], 0, 0, 0);
                    }
                }
        }
        __syncthreads();
    }
    // -------- epilogue: bias, leaky, wave-mask, split-bf16 store --------
#pragma unroll
    for (int m2 = 0; m2 < 2; ++m2) {
        int yy = y0 + 2 * wm + m2;
        if (yy >= H) continue;
#pragma unroll
        for (int n2 = 0; n2 < 2; ++n2) {
            int oc = oc0 + (2 * wn + n2) * 16 + ln;
            if (oc >= OCS) continue;
            float bv = (oc < OC) ? bias[oc] : 0.f;
#pragma unroll
            for (int r = 0; r < 4; ++r) {
                int xx = x0 + lq * 4 + r;
                float v = acc[m2][n2][r] + bv;
                if constexpr (MODE >= 1) v = v > 0.f ? v : 0.2f * v;
                if constexpr (MODE >= 2) v *= wvm[((size_t)b * H + yy) * W + xx];
                if (oc >= OC) v = 0.f;
                size_t o = (((size_t)b * H + yy) * W + xx) * OCS + oc;
                ushort h = f2bf(v);
                oHi[o] = h;
                if constexpr (SPLIT) oLo[o] = f2bf(v - bf2f(h));
            }
        }
    }
}

// ---- wave weight repack: wh[3][C][9](+wll[C][9]) -> Wv[t][CP][4] fp32 ----
__global__ __launch_bounds__(256)
void repack_wv_k(const float* __restrict__ wh, const float* __restrict__ wll,
                 float* __restrict__ out, int C, int CP)
{
    int u = blockIdx.x * 256 + threadIdx.x;
    if (u >= 9 * CP) return;
    int t = u / CP, ic = u - t * CP;
    float4 v = {0.f, 0.f, 0.f, 0.f};
    if (ic < C) {
        v.x = wh[((size_t)0 * C + ic) * 9 + t];
        v.y = wh[((size_t)1 * C + ic) * 9 + t];
        v.z = wh[((size_t)2 * C + ic) * 9 + t];
        if (wll) v.w = wll[(size_t)ic * 9 + t];
    }
    *(float4*)(out + (size_t)u * 4) = v;
}

// ---- wave convs from channel-last bf16 (hi[+lo]); one wave per pixel ----
template<int CP, int H, int W, bool SIN, bool HAS_LL>
__global__ __launch_bounds__(256)
void wave_cl_k(const ushort* __restrict__ xhi, const ushort* __restrict__ xlo,
               const float* __restrict__ wv, const float* __restrict__ bh,
               const float* __restrict__ bll, const float* __restrict__ mhalf,
               float scale, float* __restrict__ outh, float* __restrict__ outll)
{
    const int lane = threadIdx.x & 63;
    const int pix = blockIdx.x * 4 + (threadIdx.x >> 6);
    const int x = pix % W, y = (pix / W) % H, b = pix / (W * H);
    constexpr int G = CP / 8;
    float a0 = 0.f, a1 = 0.f, a2 = 0.f, a3 = 0.f;
    for (int it = lane; it < 9 * G; it += 64) {
        int t = it / G, g = it - t * G;
        int dy = t / 3 - 1, dx = t % 3 - 1;
        int yy = y + dy, xx = x + dx;
        int yc = min(max(yy, 0), H - 1), xc = min(max(xx, 0), W - 1);
        bool inr = (yy >= 0) && (yy < H) && (xx >= 0) && (xx < W);
        size_t base = (((size_t)b * H + yc) * W + xc) * CP + g * 8;
        uint4 hv = *(const uint4*)(xhi + base);
        uint4 lv = {0, 0, 0, 0};
        if constexpr (!SIN) lv = *(const uint4*)(xlo + base);
        const float4* wp = (const float4*)(wv + ((size_t)t * CP + g * 8) * 4);
        const uint* hw = (const uint*)&hv;
        const uint* lw = (const uint*)&lv;
#pragma unroll
        for (int j = 0; j < 8; ++j) {
            uint wd = hw[j >> 1];
            float xf = (j & 1) ? __uint_as_float(wd & 0xFFFF0000u)
                               : __uint_as_float(wd << 16);
            if constexpr (!SIN) {
                uint wl = lw[j >> 1];
                xf += (j & 1) ? __uint_as_float(wl & 0xFFFF0000u)
                              : __uint_as_float(wl << 16);
            }
            float xz = inr ? xf : 0.f;
            float4 w4 = wp[j];
            a0 = fmaf(w4.x, xz, a0);
            a1 = fmaf(w4.y, xz, a1);
            a2 = fmaf(w4.z, xz, a2);
            if constexpr (HAS_LL) a3 = fmaf(w4.w, xf, a3);
        }
    }
#pragma unroll
    for (int o = 1; o < 64; o <<= 1) {
        a0 += __shfl_xor(a0, o);
        a1 += __shfl_xor(a1, o);
        a2 += __shfl_xor(a2, o);
        if constexpr (HAS_LL) a3 += __shfl_xor(a3, o);
    }
    if (lane == 0) {
        float wm = 1.f;
        if (mhalf) wm = mhalf[((size_t)b * (H / 2) + (y >> 1)) * (W / 2) + (x >> 1)];
        size_t hb = (size_t)b * 3 * H * W + (size_t)y * W + x;
        outh[hb]             = (a0 + bh[0]) * scale * wm;
        outh[hb + H * W]     = (a1 + bh[1]) * scale * wm;
        outh[hb + 2 * H * W] = (a2 + bh[2]) * scale * wm;
        if constexpr (HAS_LL) outll[((size_t)b * H + y) * W + x] = (a3 + bll[0]) * 8.f;
    }
}

// ---- inverse Haar DWT ----
template<int H, int W>
__global__ __launch_bounds__(256)
void idwt_k(const float* __restrict__ ll, const float* __restrict__ h,
            float* __restrict__ out)
{
    const int g = blockIdx.x * 256 + threadIdx.x;
    constexpr int N = 4 * H * W;
    if (g >= N) return;
    const int x = g % W;
    const int y = (g / W) % H;
    const int b = g / (W * H);
    const float l  = ll[g];
    const float lh = h[((size_t)(b * 3 + 0) * H + y) * W + x];
    const float hl = h[((size_t)(b * 3 + 1) * H + y) * W + x];
    const float hh = h[((size_t)(b * 3 + 2) * H + y) * W + x];
    const float x00 = (l + lh + hl + hh) * 0.5f;
    const float x01 = (l - lh + hl - hh) * 0.5f;
    const float x10 = (l + lh - hl - hh) * 0.5f;
    const float x11 = (l - lh - hl + hh) * 0.5f;
    float* ob = out + (size_t)b * (2 * H) * (2 * W);
    ob[(size_t)(2 * y) * (2 * W) + 2 * x]         = x00;
    ob[(size_t)(2 * y) * (2 * W) + 2 * x + 1]     = x01;
    ob[(size_t)(2 * y + 1) * (2 * W) + 2 * x]     = x10;
    ob[(size_t)(2 * y + 1) * (2 * W) + 2 * x + 1] = x11;
}

__global__ __launch_bounds__(256)
void minmax_k(const float* __restrict__ p, int n, float* __restrict__ thr)
{
    __shared__ float smax[256], smin[256];
    float mx = -1e30f, mn = 1e30f;
    for (int i = threadIdx.x; i < n; i += 256) {
        const float v = p[i];
        mx = fmaxf(mx, v);
        mn = fminf(mn, v);
    }
    smax[threadIdx.x] = mx;
    smin[threadIdx.x] = mn;
    __syncthreads();
    for (int s = 128; s > 0; s >>= 1) {
        if (threadIdx.x < s) {
            smax[threadIdx.x] = fmaxf(smax[threadIdx.x], smax[threadIdx.x + s]);
            smin[threadIdx.x] = fminf(smin[threadIdx.x], smin[threadIdx.x + s]);
        }
        __syncthreads();
    }
    if (threadIdx.x == 0) *thr = (smax[0] - smin[0]) * 0.1f;
}

template<int H, int W>
__global__ __launch_bounds__(256)
void mask_k(const float* __restrict__ h, const float* __restrict__ thr,
            float* __restrict__ mask)
{
    const int g = blockIdx.x * 256 + threadIdx.x;
    constexpr int N = 4 * H * W;
    if (g >= N) return;
    const int x = g % W;
    const int y = (g / W) % H;
    const int b = g / (W * H);
    const float t  = *thr;
    const float v0 = fabsf(h[((size_t)(b * 3 + 0) * H + y) * W + x]);
    const float v1 = fabsf(h[((size_t)(b * 3 + 1) * H + y) * W + x]);
    const float v2 = fabsf(h[((size_t)(b * 3 + 2) * H + y) * W + x]);
    mask[g] = (fmaxf(v0, fmaxf(v1, v2)) > t) ? 1.f : 0.f;
}

template<int H, int W, int R>
__global__ __launch_bounds__(256)
void dilate_k(const float* __restrict__ m, float* __restrict__ o)
{
    const int g = blockIdx.x * 256 + threadIdx.x;
    constexpr int N = 4 * H * W;
    if (g >= N) return;
    const int x = g % W;
    const int y = (g / W) % H;
    const int b = g / (W * H);
    float v = 0.f;
    for (int dy = -R; dy <= R; ++dy) {
        const int yy = y + dy;
        if (yy < 0 || yy >= H) continue;
        for (int dx = -R; dx <= R; ++dx) {
            const int xx = x + dx;
            if (xx < 0 || xx >= W) continue;
            v = fmaxf(v, m[((size_t)b * H + yy) * W + xx]);
        }
    }
    o[g] = (v > 0.f) ? 1.f : 0.f;
}

template<int H, int W>
__global__ __launch_bounds__(256)
void masksfull_k(const float* __restrict__ m, float* __restrict__ conva,
                 float* __restrict__ wavem)
{
    const int g = blockIdx.x * 256 + threadIdx.x;
    constexpr int H2 = 2 * H, W2 = 2 * W;
    constexpr int N = 4 * H2 * W2;
    if (g >= N) return;
    const int x = g % W2;
    const int y = (g / W2) % H2;
    const int b = g / (W2 * H2);
    float c5 = 0.f, c3 = 0.f;
    for (int dy = -2; dy <= 2; ++dy) {
        const int yy = y + dy;
        if (yy < 0 || yy >= H2) continue;
        const int my = yy >> 1;
        for (int dx = -2; dx <= 2; ++dx) {
            const int xx = x + dx;
            if (xx < 0 || xx >= W2) continue;
            const float v = m[((size_t)b * H + my) * W + (xx >> 1)];
            c5 = fmaxf(c5, v);
            if (dy >= -1 && dy <= 1 && dx >= -1 && dx <= 1) c3 = fmaxf(c3, v);
        }
    }
    conva[g] = (c5 > 0.f) ? 1.f : 0.f;
    wavem[g] = (c3 > 0.f) ? 1.f : 0.f;
}

// ---------------------------------------------------------------------------
// workspace layout (bytes). RegionW [0, 91,570,176) is time-multiplexed:
//   phase A (before stem): Wstem hi/lo.  phase B (after stem conv):
//   Wup1 | x16 | Wup2 | x8 | Wup3 | x4 | Wv1..3, and xb overlays offset 0.
// ---------------------------------------------------------------------------
static constexpr size_t WSTEM_HI = 0;
static constexpr size_t WSTEM_LO = 45785088ull;
static constexpr size_t WUP1_HI  = 0;
static constexpr size_t WUP1_LO  = 15593472ull;
static constexpr size_t X16_HI   = 31186944ull;
static constexpr size_t X16_LO   = 35119104ull;
static constexpr size_t WUP2_HI  = 39051264ull;
static constexpr size_t WUP2_LO  = 43474944ull;
static constexpr size_t X8_HI    = 47898624ull;
static constexpr size_t X8_LO    = 55762944ull;
static constexpr size_t WUP3_HI  = 63627264ull;
static constexpr size_t X4_HI    = 64954368ull;
static constexpr size_t WV1      = 80683008ull;
static constexpr size_t WV2      = 80762496ull;
static constexpr size_t WV3      = 80802816ull;
static constexpr size_t XB_HI    = 0ull;            // overlay (Wup1/x16 dead)
static constexpr size_t X32_HI   = 91570176ull;
static constexpr size_t X32_LO   = 97222656ull;
static constexpr size_t XD0_HI   = 102875136ull;
static constexpr size_t XD0_LO   = 105701376ull;
static constexpr size_t XD1_HI   = 108527616ull;
static constexpr size_t XD1_LO   = 114180096ull;
static constexpr size_t XA_HI    = 119832576ull;
static constexpr size_t XA_LO    = 131301376ull;
static constexpr size_t F32B     = 142770176ull;
// fp32 offsets (floats, relative to F32B)
static constexpr size_t O_LL1 = 0, O_H1 = 5120, O_LLB = 20480, O_H2 = 40960;
static constexpr size_t O_LLC = 102400, O_H3 = 184320, O_M1 = 430080;
static constexpr size_t O_UPM1 = 435200, O_CAM1 = 440320, O_WM1 = 460800;
static constexpr size_t O_M2 = 481280, O_UPM2 = 501760, O_CAM2 = 522240;
static constexpr size_t O_WM2 = 604160, O_RED = 686080;

extern "C" void kernel_launch(void* const* d_in, const int* in_sizes, int n_in,
                              void* d_out, int out_size, void* d_ws, size_t ws_size,
                              hipStream_t stream)
{
    const float* x32     = (const float*)d_in[0];
    const float* x16     = (const float*)d_in[1];
    const float* x8      = (const float*)d_in[2];
    const float* x4      = (const float*)d_in[3];
    const float* conv2_w = (const float*)d_in[4];
    const float* conv2_b = (const float*)d_in[5];
    const float* up1_w   = (const float*)d_in[6];
    const float* up1_b   = (const float*)d_in[7];
    const float* w1ll_w  = (const float*)d_in[8];
    const float* w1ll_b  = (const float*)d_in[9];
    const float* w1_w    = (const float*)d_in[10];
    const float* w1_b    = (const float*)d_in[11];
    const float* up2_w   = (const float*)d_in[12];
    const float* up2_b   = (const float*)d_in[13];
    const float* w2_w    = (const float*)d_in[14];
    const float* w2_b    = (const float*)d_in[15];
    const float* up3_w   = (const float*)d_in[16];
    const float* up3_b   = (const float*)d_in[17];
    const float* w3_w    = (const float*)d_in[18];
    const float* w3_b    = (const float*)d_in[19];

    char* ws = (char*)d_ws;
    auto U = [&](size_t off) { return (ushort*)(ws + off); };
    float* f32 = (float*)(ws + F32B);
    float* ll1   = f32 + O_LL1;
    float* h1    = f32 + O_H1;
    float* llb   = f32 + O_LLB;
    float* h2    = f32 + O_H2;
    float* llc   = f32 + O_LLC;
    float* h3    = f32 + O_H3;
    float* mask1 = f32 + O_M1;
    float* upm1  = f32 + O_UPM1;
    float* cam1  = f32 + O_CAM1;
    float* wm1   = f32 + O_WM1;
    float* mask2 = f32 + O_M2;
    float* upm2  = f32 + O_UPM2;
    float* cam2  = f32 + O_CAM2;
    float* wm2   = f32 + O_WM2;
    float* red   = f32 + O_RED;
    float* wv1   = (float*)(ws + WV1);
    float* wv2   = (float*)(ws + WV2);
    float* wv3   = (float*)(ws + WV3);

    // ---- phase A: stem ----
    repack_x_k<true><<<dim3(5, 69, 4), 256, 0, stream>>>(x32, U(X32_HI), U(X32_LO), 2208, 320);
    repack_w_k<true><<<1242, 256, 0, stream>>>(conv2_w, U(WSTEM_HI), U(WSTEM_LO), 1104, 2208, 1152, 2208);
    conv_mfma_k<0, 2208, 0, 10, 32, 1104, 1104, 1152, 2208, 2208, 1, 8>
        <<<dim3(6, 18, 4), 256, 0, stream>>>(U(X32_HI), U(X32_LO), nullptr, nullptr,
            U(WSTEM_HI), U(WSTEM_LO), conv2_b, nullptr, nullptr, nullptr,
            U(XD0_HI), U(XD0_LO));
    // ---- phase B repacks (overwrite Wstem region) ----
    repack_w_k<true><<<423, 256, 0, stream>>>(up1_w, U(WUP1_HI), U(WUP1_LO), 552, 1488, 576, 1504);
    repack_x_k<true><<<dim3(20, 12, 4), 256, 0, stream>>>(x16, U(X16_HI), U(X16_LO), 384, 1280);
    repack_w_k<true><<<120, 256, 0, stream>>>(up2_w, U(WUP2_HI), U(WUP2_LO), 276, 744, 320, 768);
    repack_x_k<true><<<dim3(80, 6, 4), 256, 0, stream>>>(x8, U(X8_HI), U(X8_LO), 192, 5120);
    repack_w_k<false><<<36, 256, 0, stream>>>(up3_w, U(WUP3_HI), nullptr, 138, 372, 192, 384);
    repack_x_k<false><<<dim3(320, 3, 4), 256, 0, stream>>>(x4, U(X4_HI), nullptr, 96, 20480);
    repack_wv_k<<<20, 256, 0, stream>>>(w1_w, w1ll_w, wv1, 552, 552);
    repack_wv_k<<<10, 256, 0, stream>>>(w2_w, nullptr, wv2, 276, 280);
    repack_wv_k<<<6, 256, 0, stream>>>(w3_w, nullptr, wv3, 138, 144);
    // ---- up1 ----
    conv_mfma_k<1, 1104, 384, 20, 64, 552, 552, 576, 1504, 1104, 384, 8>
        <<<dim3(20, 9, 4), 256, 0, stream>>>(U(XD0_HI), U(XD0_LO), U(X16_HI), U(X16_LO),
            U(WUP1_HI), U(WUP1_LO), up1_b, nullptr, nullptr, nullptr,
            U(XD1_HI), U(XD1_LO));
    // ---- wave1 + level-1 masks ----
    wave_cl_k<552, 20, 64, false, true><<<1280, 256, 0, stream>>>(
        U(XD1_HI), U(XD1_LO), wv1, w1_b, w1ll_b, nullptr, 4.f, h1, ll1);
    idwt_k<20, 64><<<20, 256, 0, stream>>>(ll1, h1, llb);
    minmax_k<<<1, 256, 0, stream>>>(llb, 20480, red + 0);
    mask_k<20, 64><<<20, 256, 0, stream>>>(h1, red + 0, mask1);
    dilate_k<20, 64, 2><<<20, 256, 0, stream>>>(mask1, upm1);
    masksfull_k<20, 64><<<80, 256, 0, stream>>>(mask1, cam1, wm1);
    // ---- up2 ----
    conv_mfma_k<2, 552, 192, 40, 128, 276, 280, 320, 768, 552, 192, 8>
        <<<dim3(80, 5, 4), 256, 0, stream>>>(U(XD1_HI), U(XD1_LO), U(X8_HI), U(X8_LO),
            U(WUP2_HI), U(WUP2_LO), up2_b, upm1, cam1, wm1,
            U(XA_HI), U(XA_LO));
    // ---- wave2 + level-0 masks ----
    wave_cl_k<280, 40, 128, false, false><<<5120, 256, 0, stream>>>(
        U(XA_HI), U(XA_LO), wv2, w2_b, nullptr, mask1, 2.f, h2, nullptr);
    idwt_k<40, 128><<<80, 256, 0, stream>>>(llb, h2, llc);
    minmax_k<<<1, 256, 0, stream>>>(llc, 81920, red + 1);
    mask_k<40, 128><<<80, 256, 0, stream>>>(h2, red + 1, mask2);
    dilate_k<40, 128, 2><<<80, 256, 0, stream>>>(mask2, upm2);
    masksfull_k<40, 128><<<320, 256, 0, stream>>>(mask2, cam2, wm2);
    // ---- up3 (single-bf16) ----
    conv_mfma_k<3, 276, 96, 80, 256, 138, 144, 192, 384, 280, 96, 4>
        <<<dim3(320, 3, 4), 256, 0, stream>>>(U(XA_HI), nullptr, U(X4_HI), nullptr,
            U(WUP3_HI), nullptr, up3_b, upm2, cam2, wm2,
            U(XB_HI), nullptr);
    // ---- wave3 + final idwt ----
    wave_cl_k<144, 80, 256, true, false><<<20480, 256, 0, stream>>>(
        U(XB_HI), nullptr, wv3, w3_b, nullptr, mask2, 1.f, h3, nullptr);
    idwt_k<80, 256><<<320, 256, 0, stream>>>(llc, h3, (float*)d_out);
}

// Round 4
// 2552.480 us; speedup vs baseline: 5.3379x; 1.3189x over previous
//
#include <hip/hip_runtime.h>
#include <hip/hip_bf16.h>
#include <stdint.h>

// ---------------------------------------------------------------------------
// SparseDecoderWave — MFMA bf16 implicit-GEMM, 3-segment K-stacked split.
// K layout per conv: [A_hi | A_lo | A_hi] x [W_hi | W_hi | W_lo]  (SEG=3)
//   => ah*wh + al*wh + ah*wl  (full double-bf16 cross terms, err ~2^-16).
// up3 is single-bf16 (SEG=1). Weights staged via LDS once per block.
// ---------------------------------------------------------------------------

typedef float f32x4 __attribute__((ext_vector_type(4)));
typedef short s16x8 __attribute__((ext_vector_type(8)));

__device__ __forceinline__ ushort f2bf(float f) {
    uint32_t u = __float_as_uint(f);
    u += 0x7FFFu + ((u >> 16) & 1u);
    return (ushort)(u >> 16);
}
__device__ __forceinline__ float bf2f(ushort h) {
    return __uint_as_float(((uint32_t)h) << 16);
}

// ---- weight repack: w[oc][ct][3][3] fp32 -> W'[t][OCP][KT] bf16 ----
// A region: seg 0/1 = hi, seg 2 = lo residual; B region likewise.
__global__ __launch_bounds__(256)
void repack_w_k(const float* __restrict__ w, ushort* __restrict__ out,
                int OC, int CT, int ICOFF, int CAR, int CAP, int CAT,
                int CBR, int CBP, int SEG, int OCP, int KT)
{
    const int KG = KT / 8;
    const int u = blockIdx.x * 256 + threadIdx.x;
    if (u >= OCP * KG) return;
    const int oc = u / KG, kg = u - oc * KG;
    const int k0 = kg * 8;
    int ic, lo; bool ok;
    if (k0 < SEG * CAP) {
        const int seg = k0 / CAP, c = k0 - seg * CAP;
        lo = (seg == 2); ic = ICOFF + c; ok = (c < CAR);
    } else {
        const int kb = k0 - SEG * CAP;
        const int seg = kb / CBP, c = kb - seg * CBP;
        lo = (seg == 2); ic = CAT + c; ok = (c < CBR);
    }
    ok = ok && (oc < OC);
    for (int t = 0; t < 9; ++t) {
        ushort q[8];
#pragma unroll
        for (int j = 0; j < 8; ++j) q[j] = 0;
        if (ok) {
#pragma unroll
            for (int j = 0; j < 8; ++j) {
                const float v = w[((size_t)oc * CT + ic + j) * 9 + t];
                const ushort h = f2bf(v);
                q[j] = lo ? f2bf(v - bf2f(h)) : h;
            }
        }
        *(uint4*)(out + ((size_t)t * OCP + oc) * KT + k0) = *(uint4*)q;
    }
}

// ---- input repack: [b][c][p] fp32 -> [b][p][OST] bf16 hi(+lo at LOOFF) ----
template<bool SPLIT>
__global__ __launch_bounds__(256)
void repack_x_k(const float* __restrict__ in, ushort* __restrict__ out,
                int C, int HW, int OST, int LOOFF)
{
    __shared__ float tile[32][65];
    const int b = blockIdx.z, c0 = blockIdx.y * 32, p0 = blockIdx.x * 64;
    for (int e = threadIdx.x; e < 2048; e += 256) {
        const int cl = e >> 6, pl = e & 63;
        tile[cl][pl] = in[((size_t)b * C + c0 + cl) * HW + p0 + pl];
    }
    __syncthreads();
    const int pl = threadIdx.x >> 2, cg = (threadIdx.x & 3) * 8;
    ushort hv[8], lv[8];
#pragma unroll
    for (int j = 0; j < 8; ++j) {
        const float v = tile[cg + j][pl];
        const ushort h = f2bf(v);
        hv[j] = h;
        lv[j] = f2bf(v - bf2f(h));
    }
    const size_t o = ((size_t)b * HW + p0 + pl) * OST + c0 + cg;
    *(uint4*)(out + o) = *(uint4*)hv;
    if constexpr (SPLIT) *(uint4*)(out + LOOFF + o) = *(uint4*)lv;
}

// ---- MFMA conv3x3, LDS-staged weights + A-halo tile ----
// MODE 0: edge pad (stem); MODE 1: reflect, A up2x (up1);
// MODE 2: reflect, A up2x, masked staging + leaky*wvm epilogue (up2/up3).
template<int MODE, int WR, int WC, int WROWS, int WCOLF, int NOCF,
         int H, int W, int OCP, int KT, int CAP, int CBP, int SEG,
         int ASTR, int APLSTR, int AOFF, int CAR, int BSTR, int KS,
         bool SOUT, bool ACCIN>
__global__ __launch_bounds__(256, 1)
void conv_mfma_k(const ushort* __restrict__ xA, const ushort* __restrict__ xB,
                 const ushort* __restrict__ wgt, const float* __restrict__ bias,
                 const float* __restrict__ upm, const float* __restrict__ cam,
                 const float* __restrict__ wvm,
                 ushort* __restrict__ outb, float* __restrict__ outp, int OC)
{
    constexpr int BROWS = WR * WROWS;          // block rows
    constexpr int NOC = NOCF * 16;             // oc per block
    constexpr int PH = BROWS + 2, PW = 34;     // halo tile (block cols = 32)
    constexpr int NPX = PH * PW;
    constexpr int ICS = 40;                    // LDS pixel stride (ushorts)
    constexpr int WRS = 40;                    // LDS weight row stride
    constexpr int NAU = NPX * 4;
    constexpr int NWU = 9 * NOC * 4;
    constexpr int NSA = (NAU + 255) / 256;
    constexpr int NSW = (NWU + 255) / 256;
    constexpr int NCH = KT / 32;
    constexpr int XT = W / 32;
    constexpr int HP = ((H + BROWS - 1) / BROWS) * BROWS;
    constexpr int HA = (MODE == 0) ? H : H / 2;
    constexpr int WA = (MODE == 0) ? W : W / 2;

    __shared__ __align__(16) ushort atile[NPX * ICS];
    __shared__ __align__(16) ushort wtile[9 * NOC * WRS];

    const int tid = threadIdx.x;
    const int b = blockIdx.z / KS, sid = blockIdx.z % KS;
    const int oc0 = blockIdx.y * NOC;
    const int y0 = (blockIdx.x / XT) * BROWS;
    const int x0 = (blockIdx.x % XT) * 32;
    const int lane = tid & 63, wv = tid >> 6;
    const int wr = wv / WC, wc = wv % WC;
    const int lq = lane >> 4, ln = lane & 15;
    const int wcb = wc * (WCOLF * 16);

    const int c0 = (sid * NCH) / KS, c1 = ((sid + 1) * NCH) / KS;

    // ---- A staging geometry (k-independent) ----
    int aBA[NSA], aBB[NSA], aLD[NSA], aKO[NSA];
    bool agA[NSA], agB[NSA];
    for (int s = 0; s < NSA; ++s) {
        const int u = tid + s * 256;
        const bool val = u < NAU;
        const int uc = val ? u : 0;
        const int pp = uc >> 2, ug = uc & 3;
        const int py = pp / PW, px = pp - py * PW;
        int y = y0 + py - 1, x = x0 + px - 1;
        if (MODE == 0) { y = min(max(y, 0), H - 1); x = min(max(x, 0), W - 1); }
        else { y = (y < 0) ? -y : ((y >= H) ? 2 * H - 2 - y : y);
               x = (x < 0) ? -x : ((x >= W) ? 2 * W - 2 - x : x); }
        const int ya = (MODE == 0) ? y : (y >> 1);
        const int xa = (MODE == 0) ? x : (x >> 1);
        aBA[s] = ((b * HA + ya) * WA + xa) * ASTR;
        aBB[s] = ((b * H + y) * W + x) * BSTR;
        agA[s] = val; agB[s] = val;
        if (MODE == 2) {
            const float cm = cam[((size_t)b * H + y) * W + x];
            const float um = upm[((size_t)b * HA + ya) * WA + xa];
            agA[s] = agA[s] && (um * cm != 0.f);
            agB[s] = agB[s] && (cm != 0.f);
        }
        aLD[s] = pp * ICS + ug * 8;
        aKO[s] = ug * 8;
    }
    // ---- W staging geometry ----
    int wGB[NSW], wLD[NSW]; bool wVv[NSW];
    for (int s = 0; s < NSW; ++s) {
        const int u = tid + s * 256;
        wVv[s] = u < NWU;
        const int uc = wVv[s] ? u : 0;
        const int t = uc / (NOC * 4), r = uc - t * (NOC * 4);
        const int ocl = r >> 2, kg = r & 3;
        wGB[s] = (t * OCP + oc0 + ocl) * KT + kg * 8;
        wLD[s] = (t * NOC + ocl) * WRS + kg * 8;
    }

    uint4 ra[NSA], rw[NSW];
    auto fetch = [&](int kc) {
#pragma unroll
        for (int s = 0; s < NSA; ++s) {
            const int k = kc * 32 + aKO[s];
            uint4 v = {0, 0, 0, 0};
            if (k < SEG * CAP) {
                int ka = (SEG == 3 && k >= 2 * CAP) ? k - 2 * CAP : k;
                const int pl = (ka >= CAP) ? 1 : 0;
                const int c = ka - pl * CAP;
                bool ok = agA[s];
                if (CAR < CAP) ok = ok && (c < CAR);
                if (ok) v = *(const uint4*)(xA + (size_t)aBA[s] + pl * APLSTR + AOFF + c);
            } else {
                int kb = k - SEG * CAP;
                if (SEG == 3 && kb >= 2 * CBP) kb -= 2 * CBP;
                if (agB[s]) v = *(const uint4*)(xB + (size_t)aBB[s] + kb);
            }
            ra[s] = v;
        }
#pragma unroll
        for (int s = 0; s < NSW; ++s) {
            uint4 v = {0, 0, 0, 0};
            if (wVv[s]) v = *(const uint4*)(wgt + (size_t)wGB[s] + kc * 32);
            rw[s] = v;
        }
    };
    auto put = [&]() {
#pragma unroll
        for (int s = 0; s < NSA; ++s)
            if (tid + s * 256 < NAU) *(uint4*)&atile[aLD[s]] = ra[s];
#pragma unroll
        for (int s = 0; s < NSW; ++s)
            if (wVv[s]) *(uint4*)&wtile[wLD[s]] = rw[s];
    };

    f32x4 acc[WROWS][WCOLF][NOCF];
#pragma unroll
    for (int i = 0; i < WROWS; ++i)
#pragma unroll
        for (int c = 0; c < WCOLF; ++c)
#pragma unroll
            for (int n = 0; n < NOCF; ++n) acc[i][c][n] = {0.f, 0.f, 0.f, 0.f};

    if (ACCIN) {
#pragma unroll
        for (int ri = 0; ri < WROWS; ++ri) {
            const float* Pr = outp +
                ((((size_t)sid * 4 + b) * HP + y0 + wr * WROWS + ri) * W + x0 + wcb) * OCP;
#pragma unroll
            for (int cf = 0; cf < WCOLF; ++cf)
#pragma unroll
                for (int n2 = 0; n2 < NOCF; ++n2)
#pragma unroll
                    for (int r = 0; r < 4; ++r)
                        acc[ri][cf][n2][r] =
                            Pr[(size_t)(cf * 16 + lq * 4 + r) * OCP + oc0 + n2 * 16 + ln];
        }
    }

    fetch(c0);
    put();
    __syncthreads();

    for (int kc = c0; kc < c1; ++kc) {
        const bool hn = (kc + 1 < c1);
        if (hn) fetch(kc + 1);
        // ---- preload A fragments ----
        s16x8 afr[WROWS + 2][WCOLF][3];
#pragma unroll
        for (int ar = 0; ar < WROWS + 2; ++ar)
#pragma unroll
            for (int cf = 0; cf < WCOLF; ++cf)
#pragma unroll
                for (int dx = 0; dx < 3; ++dx)
                    afr[ar][cf][dx] = *(const s16x8*)
                        &atile[((wr * WROWS + ar) * PW + wcb + cf * 16 + ln + dx) * ICS + lq * 8];
        // ---- 9 taps ----
#pragma unroll
        for (int t = 0; t < 9; ++t) {
            const int dy = t / 3, dx = t - dy * 3;
#pragma unroll
            for (int n2 = 0; n2 < NOCF; ++n2) {
                const s16x8 bw = *(const s16x8*)
                    &wtile[(t * NOC + n2 * 16 + ln) * WRS + lq * 8];
#pragma unroll
                for (int ri = 0; ri < WROWS; ++ri)
#pragma unroll
                    for (int cf = 0; cf < WCOLF; ++cf)
                        acc[ri][cf][n2] = __builtin_amdgcn_mfma_f32_16x16x32_bf16(
                            afr[ri + dy][cf][dx], bw, acc[ri][cf][n2], 0, 0, 0);
            }
        }
        __syncthreads();
        if (hn) { put(); __syncthreads(); }
    }

    // ---- epilogue ----
    if (KS > 1) {
#pragma unroll
        for (int ri = 0; ri < WROWS; ++ri) {
            float* Pr = outp +
                ((((size_t)sid * 4 + b) * HP + y0 + wr * WROWS + ri) * W + x0 + wcb) * OCP;
#pragma unroll
            for (int cf = 0; cf < WCOLF; ++cf)
#pragma unroll
                for (int n2 = 0; n2 < NOCF; ++n2)
#pragma unroll
                    for (int r = 0; r < 4; ++r)
                        Pr[(size_t)(cf * 16 + lq * 4 + r) * OCP + oc0 + n2 * 16 + ln] =
                            acc[ri][cf][n2][r];
        }
    } else {
        constexpr int OST = SOUT ? 2 * OCP : OCP;
#pragma unroll
        for (int ri = 0; ri < WROWS; ++ri) {
            const int y = y0 + wr * WROWS + ri;
#pragma unroll
            for (int cf = 0; cf < WCOLF; ++cf)
#pragma unroll
                for (int n2 = 0; n2 < NOCF; ++n2) {
                    const int oc = oc0 + n2 * 16 + ln;
                    const float bv = (oc < OC) ? bias[oc] : 0.f;
#pragma unroll
                    for (int r = 0; r < 4; ++r) {
                        const int x = x0 + wcb + cf * 16 + lq * 4 + r;
                        float v = acc[ri][cf][n2][r] + bv;
                        v = v > 0.f ? v : 0.2f * v;
                        v *= wvm[((size_t)b * H + y) * W + x];
                        if (oc >= OC) v = 0.f;
                        const size_t o = (((size_t)b * H + y) * W + x) * OST + oc;
                        const ushort h = f2bf(v);
                        outb[o] = h;
                        if constexpr (SOUT) outb[o + OCP] = f2bf(v - bf2f(h));
                    }
                }
        }
    }
}

// ---- split-K reduce: sum fp32 partials, bias(+leaky), bf16 hi/lo store ----
template<int KS, int HP, int H, int W, int OCP, bool ACT>
__global__ __launch_bounds__(256)
void reduce_k(const float* __restrict__ P, const float* __restrict__ bias,
              ushort* __restrict__ out, int OC)
{
    constexpr int OG = OCP / 4;
    const int u = blockIdx.x * 256 + threadIdx.x;
    if (u >= 4 * H * W * OG) return;
    const int og = u % OG;
    const int px = u / OG;
    const int x = px % W, y = (px / W) % H, b = px / (W * H);
    float4 s = {0.f, 0.f, 0.f, 0.f};
    for (int sid = 0; sid < KS; ++sid) {
        const float4 v = *(const float4*)
            (P + ((((size_t)sid * 4 + b) * HP + y) * W + x) * OCP + og * 4);
        s.x += v.x; s.y += v.y; s.z += v.z; s.w += v.w;
    }
    const int oc = og * 4;
    const float vv[4] = {s.x, s.y, s.z, s.w};
    ushort hi[4], lo[4];
#pragma unroll
    for (int j = 0; j < 4; ++j) {
        float v = (oc + j < OC) ? vv[j] + bias[oc + j] : 0.f;
        if (ACT) v = v > 0.f ? v : 0.2f * v;
        const ushort h = f2bf(v);
        hi[j] = h;
        lo[j] = f2bf(v - bf2f(h));
    }
    const size_t o = (size_t)px * 2 * OCP + oc;
    *(uint2*)(out + o) = *(uint2*)hi;
    *(uint2*)(out + o + OCP) = *(uint2*)lo;
}

// ---- wave weight repack: wh[3][C][9](+wll[C][9]) -> Wv[t][CP][4] fp32 ----
__global__ __launch_bounds__(256)
void repack_wv_k(const float* __restrict__ wh, const float* __restrict__ wll,
                 float* __restrict__ out, int C, int CP)
{
    const int u = blockIdx.x * 256 + threadIdx.x;
    if (u >= 9 * CP) return;
    const int t = u / CP, ic = u - t * CP;
    float4 v = {0.f, 0.f, 0.f, 0.f};
    if (ic < C) {
        v.x = wh[((size_t)0 * C + ic) * 9 + t];
        v.y = wh[((size_t)1 * C + ic) * 9 + t];
        v.z = wh[((size_t)2 * C + ic) * 9 + t];
        if (wll) v.w = wll[(size_t)ic * 9 + t];
    }
    *(float4*)(out + (size_t)u * 4) = v;
}

// ---- wave convs from channel-last bf16 (hi at +0, lo at +LOOFF) ----
template<int G, int CSTR, int LOOFF, int H, int W, bool SIN, bool HAS_LL>
__global__ __launch_bounds__(256)
void wave_cl_k(const ushort* __restrict__ xq, const float* __restrict__ wv,
               const float* __restrict__ bh, const float* __restrict__ bll,
               const float* __restrict__ mhalf, float scale,
               float* __restrict__ outh, float* __restrict__ outll)
{
    const int lane = threadIdx.x & 63;
    const int pix = blockIdx.x * 4 + (threadIdx.x >> 6);
    const int x = pix % W, y = (pix / W) % H, b = pix / (W * H);
    float a0 = 0.f, a1 = 0.f, a2 = 0.f, a3 = 0.f;
    for (int it = lane; it < 9 * G; it += 64) {
        const int t = it / G, g = it - t * G;
        const int dy = t / 3 - 1, dx = t % 3 - 1;
        const int yy = y + dy, xx = x + dx;
        const int yc = min(max(yy, 0), H - 1), xc = min(max(xx, 0), W - 1);
        const bool inr = (yy >= 0) && (yy < H) && (xx >= 0) && (xx < W);
        const size_t base = (((size_t)b * H + yc) * W + xc) * CSTR + g * 8;
        const uint4 hv = *(const uint4*)(xq + base);
        uint4 lv = {0, 0, 0, 0};
        if constexpr (!SIN) lv = *(const uint4*)(xq + base + LOOFF);
        const float4* wp = (const float4*)(wv + ((size_t)t * (G * 8) + g * 8) * 4);
        const uint* hw = (const uint*)&hv;
        const uint* lw = (const uint*)&lv;
#pragma unroll
        for (int j = 0; j < 8; ++j) {
            const uint wd = hw[j >> 1];
            float xf = (j & 1) ? __uint_as_float(wd & 0xFFFF0000u)
                               : __uint_as_float(wd << 16);
            if constexpr (!SIN) {
                const uint wl = lw[j >> 1];
                xf += (j & 1) ? __uint_as_float(wl & 0xFFFF0000u)
                              : __uint_as_float(wl << 16);
            }
            const float xz = inr ? xf : 0.f;
            const float4 w4 = wp[j];
            a0 = fmaf(w4.x, xz, a0);
            a1 = fmaf(w4.y, xz, a1);
            a2 = fmaf(w4.z, xz, a2);
            if constexpr (HAS_LL) a3 = fmaf(w4.w, xf, a3);
        }
    }
#pragma unroll
    for (int o = 1; o < 64; o <<= 1) {
        a0 += __shfl_xor(a0, o);
        a1 += __shfl_xor(a1, o);
        a2 += __shfl_xor(a2, o);
        if constexpr (HAS_LL) a3 += __shfl_xor(a3, o);
    }
    if (lane == 0) {
        float wm = 1.f;
        if (mhalf) wm = mhalf[((size_t)b * (H / 2) + (y >> 1)) * (W / 2) + (x >> 1)];
        const size_t hb = (size_t)b * 3 * H * W + (size_t)y * W + x;
        outh[hb]             = (a0 + bh[0]) * scale * wm;
        outh[hb + H * W]     = (a1 + bh[1]) * scale * wm;
        outh[hb + 2 * H * W] = (a2 + bh[2]) * scale * wm;
        if constexpr (HAS_LL) outll[((size_t)b * H + y) * W + x] = (a3 + bll[0]) * 8.f;
    }
}

// ---- inverse Haar DWT ----
template<int H, int W>
__global__ __launch_bounds__(256)
void idwt_k(const float* __restrict__ ll, const float* __restrict__ h,
            float* __restrict__ out)
{
    const int g = blockIdx.x * 256 + threadIdx.x;
    if (g >= 4 * H * W) return;
    const int x = g % W, y = (g / W) % H, b = g / (W * H);
    const float l  = ll[g];
    const float lh = h[((size_t)(b * 3 + 0) * H + y) * W + x];
    const float hl = h[((size_t)(b * 3 + 1) * H + y) * W + x];
    const float hh = h[((size_t)(b * 3 + 2) * H + y) * W + x];
    const float x00 = (l + lh + hl + hh) * 0.5f;
    const float x01 = (l - lh + hl - hh) * 0.5f;
    const float x10 = (l + lh - hl - hh) * 0.5f;
    const float x11 = (l - lh - hl + hh) * 0.5f;
    float* ob = out + (size_t)b * (2 * H) * (2 * W);
    ob[(size_t)(2 * y) * (2 * W) + 2 * x]         = x00;
    ob[(size_t)(2 * y) * (2 * W) + 2 * x + 1]     = x01;
    ob[(size_t)(2 * y + 1) * (2 * W) + 2 * x]     = x10;
    ob[(size_t)(2 * y + 1) * (2 * W) + 2 * x + 1] = x11;
}

__global__ __launch_bounds__(256)
void minmax_k(const float* __restrict__ p, int n, float* __restrict__ thr)
{
    __shared__ float smax[256], smin[256];
    float mx = -1e30f, mn = 1e30f;
    for (int i = threadIdx.x; i < n; i += 256) {
        const float v = p[i];
        mx = fmaxf(mx, v);
        mn = fminf(mn, v);
    }
    smax[threadIdx.x] = mx;
    smin[threadIdx.x] = mn;
    __syncthreads();
    for (int s = 128; s > 0; s >>= 1) {
        if (threadIdx.x < s) {
            smax[threadIdx.x] = fmaxf(smax[threadIdx.x], smax[threadIdx.x + s]);
            smin[threadIdx.x] = fminf(smin[threadIdx.x], smin[threadIdx.x + s]);
        }
        __syncthreads();
    }
    if (threadIdx.x == 0) *thr = (smax[0] - smin[0]) * 0.1f;
}

template<int H, int W>
__global__ __launch_bounds__(256)
void mask_k(const float* __restrict__ h, const float* __restrict__ thr,
            float* __restrict__ mask)
{
    const int g = blockIdx.x * 256 + threadIdx.x;
    if (g >= 4 * H * W) return;
    const int x = g % W, y = (g / W) % H, b = g / (W * H);
    const float t  = *thr;
    const float v0 = fabsf(h[((size_t)(b * 3 + 0) * H + y) * W + x]);
    const float v1 = fabsf(h[((size_t)(b * 3 + 1) * H + y) * W + x]);
    const float v2 = fabsf(h[((size_t)(b * 3 + 2) * H + y) * W + x]);
    mask[g] = (fmaxf(v0, fmaxf(v1, v2)) > t) ? 1.f : 0.f;
}

template<int H, int W, int R>
__global__ __launch_bounds__(256)
void dilate_k(const float* __restrict__ m, float* __restrict__ o)
{
    const int g = blockIdx.x * 256 + threadIdx.x;
    if (g >= 4 * H * W) return;
    const int x = g % W, y = (g / W) % H, b = g / (W * H);
    float v = 0.f;
    for (int dy = -R; dy <= R; ++dy) {
        const int yy = y + dy;
        if (yy < 0 || yy >= H) continue;
        for (int dx = -R; dx <= R; ++dx) {
            const int xx = x + dx;
            if (xx < 0 || xx >= W) continue;
            v = fmaxf(v, m[((size_t)b * H + yy) * W + xx]);
        }
    }
    o[g] = (v > 0.f) ? 1.f : 0.f;
}

template<int H, int W>
__global__ __launch_bounds__(256)
void masksfull_k(const float* __restrict__ m, float* __restrict__ conva,
                 float* __restrict__ wavem)
{
    const int g = blockIdx.x * 256 + threadIdx.x;
    constexpr int H2 = 2 * H, W2 = 2 * W;
    if (g >= 4 * H2 * W2) return;
    const int x = g % W2, y = (g / W2) % H2, b = g / (W2 * H2);
    float c5 = 0.f, c3 = 0.f;
    for (int dy = -2; dy <= 2; ++dy) {
        const int yy = y + dy;
        if (yy < 0 || yy >= H2) continue;
        const int my = yy >> 1;
        for (int dx = -2; dx <= 2; ++dx) {
            const int xx = x + dx;
            if (xx < 0 || xx >= W2) continue;
            const float v = m[((size_t)b * H + my) * W + (xx >> 1)];
            c5 = fmaxf(c5, v);
            if (dy >= -1 && dy <= 1 && dx >= -1 && dx <= 1) c3 = fmaxf(c3, v);
        }
    }
    conva[g] = (c5 > 0.f) ? 1.f : 0.f;
    wavem[g] = (c3 > 0.f) ? 1.f : 0.f;
}

// ---------------------------------------------------------------------------
// workspace layout (bytes)
// ---------------------------------------------------------------------------
static constexpr size_t WSTEM = 0;             // 66,769,920 (9*1104*3360*2), both phases
static constexpr size_t WUP1  = 0;             // 46,780,416 (9*576*4512*2)
static constexpr size_t X16   = 46780416ull;   // 7,864,320
static constexpr size_t WUP2  = 54644736ull;   // 11,943,936 (9*288*2304*2) end 66,588,672
static constexpr size_t XB    = 0ull;          // 23,592,960 (over WUP1, dead)
static constexpr size_t X4    = 23592960ull;   // 15,728,640 (over WUP1, dead) end 39,321,600
static constexpr size_t WUP3  = 66769920ull;   // 995,328  (over X32, dead)
static constexpr size_t WV1   = 67765248ull;   // 79,488
static constexpr size_t WV2   = 67844736ull;   // 40,320
static constexpr size_t WV3   = 67885056ull;   // 20,736 end 67,905,792
static constexpr size_t X32   = 66769920ull;   // 11,304,960 end 78,074,880
static constexpr size_t XD0   = 78074880ull;   // 5,652,480  end 83,727,360
static constexpr size_t PF    = 83727360ull;   // 27,131,904 (stem P; up1 P; then XA)
static constexpr size_t XAOF  = 83727360ull;   // 23,592,960
static constexpr size_t XD1   = 110859264ull;  // 11,796,480 end 122,655,744
static constexpr size_t X8    = 122655744ull;  // 15,728,640 end 138,384,384
static constexpr size_t F32B  = 138384384ull;
static constexpr size_t O_LL1 = 0, O_H1 = 5120, O_LLB = 20480, O_H2 = 40960;
static constexpr size_t O_LLC = 102400, O_H3 = 184320, O_M1 = 430080;
static constexpr size_t O_UPM1 = 435200, O_CAM1 = 440320, O_WM1 = 460800;
static constexpr size_t O_M2 = 481280, O_UPM2 = 501760, O_CAM2 = 522240;
static constexpr size_t O_WM2 = 604160, O_RED = 686080;

extern "C" void kernel_launch(void* const* d_in, const int* in_sizes, int n_in,
                              void* d_out, int out_size, void* d_ws, size_t ws_size,
                              hipStream_t stream)
{
    const float* x32     = (const float*)d_in[0];
    const float* x16     = (const float*)d_in[1];
    const float* x8      = (const float*)d_in[2];
    const float* x4      = (const float*)d_in[3];
    const float* conv2_w = (const float*)d_in[4];
    const float* conv2_b = (const float*)d_in[5];
    const float* up1_w   = (const float*)d_in[6];
    const float* up1_b   = (const float*)d_in[7];
    const float* w1ll_w  = (const float*)d_in[8];
    const float* w1ll_b  = (const float*)d_in[9];
    const float* w1_w    = (const float*)d_in[10];
    const float* w1_b    = (const float*)d_in[11];
    const float* up2_w   = (const float*)d_in[12];
    const float* up2_b   = (const float*)d_in[13];
    const float* w2_w    = (const float*)d_in[14];
    const float* w2_b    = (const float*)d_in[15];
    const float* up3_w   = (const float*)d_in[16];
    const float* up3_b   = (const float*)d_in[17];
    const float* w3_w    = (const float*)d_in[18];
    const float* w3_b    = (const float*)d_in[19];

    char* ws = (char*)d_ws;
    auto U = [&](size_t off) { return (ushort*)(ws + off); };
    float* Pf  = (float*)(ws + PF);
    float* f32 = (float*)(ws + F32B);
    float* ll1   = f32 + O_LL1;
    float* h1    = f32 + O_H1;
    float* llb   = f32 + O_LLB;
    float* h2    = f32 + O_H2;
    float* llc   = f32 + O_LLC;
    float* h3    = f32 + O_H3;
    float* mask1 = f32 + O_M1;
    float* upm1  = f32 + O_UPM1;
    float* cam1  = f32 + O_CAM1;
    float* wm1   = f32 + O_WM1;
    float* mask2 = f32 + O_M2;
    float* upm2  = f32 + O_UPM2;
    float* cam2  = f32 + O_CAM2;
    float* wm2   = f32 + O_WM2;
    float* wv1   = (float*)(ws + WV1);
    float* wv2   = (float*)(ws + WV2);
    float* wv3   = (float*)(ws + WV3);

    // ---- stem: 2 IC-phases (weights re-staged), split-K 4, RMW partials ----
    repack_x_k<true><<<dim3(5, 69, 4), 256, 0, stream>>>(x32, U(X32), 2208, 320, 4416, 2208);
    repack_w_k<<<1812, 256, 0, stream>>>(conv2_w, U(WSTEM), 1104, 2208, 0, 1104, 1120, 0, 0, 8, 3, 1104, 3360);
    conv_mfma_k<0, 2, 2, 2, 1, 3, 10, 32, 1104, 3360, 1120, 8, 3, 4416, 2208, 0, 1104, 1, 4, false, false>
        <<<dim3(3, 23, 16), 256, 0, stream>>>(U(X32), nullptr, U(WSTEM), nullptr,
            nullptr, nullptr, nullptr, nullptr, Pf, 1104);
    repack_w_k<<<1812, 256, 0, stream>>>(conv2_w, U(WSTEM), 1104, 2208, 1104, 1104, 1120, 0, 0, 8, 3, 1104, 3360);
    conv_mfma_k<0, 2, 2, 2, 1, 3, 10, 32, 1104, 3360, 1120, 8, 3, 4416, 2208, 1104, 1104, 1, 4, false, true>
        <<<dim3(3, 23, 16), 256, 0, stream>>>(U(X32), nullptr, U(WSTEM), nullptr,
            nullptr, nullptr, nullptr, nullptr, Pf, 1104);
    reduce_k<4, 12, 10, 32, 1104, false><<<1380, 256, 0, stream>>>(Pf, conv2_b, U(XD0), 1104);
    // ---- phase B repacks (WSTEM/X32 regions now dead) ----
    repack_w_k<<<1269, 256, 0, stream>>>(up1_w, U(WUP1), 552, 1488, 0, 1104, 1120, 1104, 384, 384, 3, 576, 4512);
    repack_x_k<true><<<dim3(20, 12, 4), 256, 0, stream>>>(x16, U(X16), 384, 1280, 768, 384);
    repack_w_k<<<324, 256, 0, stream>>>(up2_w, U(WUP2), 276, 744, 0, 552, 576, 552, 192, 192, 3, 288, 2304);
    repack_w_k<<<27, 256, 0, stream>>>(up3_w, U(WUP3), 138, 372, 0, 276, 288, 276, 96, 96, 1, 144, 384);
    repack_x_k<true><<<dim3(80, 6, 4), 256, 0, stream>>>(x8, U(X8), 192, 5120, 384, 192);
    repack_wv_k<<<20, 256, 0, stream>>>(w1_w, w1ll_w, wv1, 552, 552);
    repack_wv_k<<<10, 256, 0, stream>>>(w2_w, nullptr, wv2, 276, 280);
    repack_wv_k<<<6, 256, 0, stream>>>(w3_w, nullptr, wv3, 138, 144);
    // ---- up1 (split-K 2) ----
    conv_mfma_k<1, 2, 2, 2, 1, 4, 20, 64, 576, 4512, 1120, 384, 3, 2208, 1104, 0, 1104, 768, 2, false, false>
        <<<dim3(10, 9, 8), 256, 0, stream>>>(U(XD0), U(X16), U(WUP1), nullptr,
            nullptr, nullptr, nullptr, nullptr, Pf, 552);
    reduce_k<2, 20, 20, 64, 576, true><<<2880, 256, 0, stream>>>(Pf, up1_b, U(XD1), 552);
    repack_x_k<false><<<dim3(320, 3, 4), 256, 0, stream>>>(x4, U(X4), 96, 20480, 96, 0);
    // ---- wave1 + level-1 masks ----
    wave_cl_k<69, 1152, 576, 20, 64, false, true><<<1280, 256, 0, stream>>>(
        U(XD1), wv1, w1_b, w1ll_b, nullptr, 4.f, h1, ll1);
    idwt_k<20, 64><<<20, 256, 0, stream>>>(ll1, h1, llb);
    minmax_k<<<1, 256, 0, stream>>>(llb, 20480, f32 + O_RED);
    mask_k<20, 64><<<20, 256, 0, stream>>>(h1, f32 + O_RED, mask1);
    dilate_k<20, 64, 2><<<20, 256, 0, stream>>>(mask1, upm1);
    masksfull_k<20, 64><<<80, 256, 0, stream>>>(mask1, cam1, wm1);
    // ---- up2 ----
    conv_mfma_k<2, 4, 1, 2, 2, 3, 40, 128, 288, 2304, 576, 192, 3, 1152, 576, 0, 576, 384, 1, true, false>
        <<<dim3(20, 6, 4), 256, 0, stream>>>(U(XD1), U(X8), U(WUP2), up2_b,
            upm1, cam1, wm1, U(XAOF), nullptr, 276);
    // ---- wave2 + level-0 masks ----
    wave_cl_k<35, 576, 288, 40, 128, false, false><<<5120, 256, 0, stream>>>(
        U(XAOF), wv2, w2_b, nullptr, mask1, 2.f, h2, nullptr);
    idwt_k<40, 128><<<80, 256, 0, stream>>>(llb, h2, llc);
    minmax_k<<<1, 256, 0, stream>>>(llc, 81920, f32 + O_RED + 1);
    mask_k<40, 128><<<80, 256, 0, stream>>>(h2, f32 + O_RED + 1, mask2);
    dilate_k<40, 128, 2><<<80, 256, 0, stream>>>(mask2, upm2);
    masksfull_k<40, 128><<<320, 256, 0, stream>>>(mask2, cam2, wm2);
    // ---- up3 (single bf16) ----
    conv_mfma_k<2, 4, 1, 2, 2, 3, 80, 256, 144, 384, 288, 96, 1, 576, 288, 0, 288, 96, 1, false, false>
        <<<dim3(80, 3, 4), 256, 0, stream>>>(U(XAOF), U(X4), U(WUP3), up3_b,
            upm2, cam2, wm2, U(XB), nullptr, 138);
    // ---- wave3 + final idwt ----
    wave_cl_k<18, 144, 0, 80, 256, true, false><<<20480, 256, 0, stream>>>(
        U(XB), wv3, w3_b, nullptr, mask2, 1.f, h3, nullptr);
    idwt_k<80, 256><<<320, 256, 0, stream>>>(llc, h3, (float*)d_out);
}